// Round 1
// 349.368 us; speedup vs baseline: 1.0086x; 1.0086x over previous
//
#include <hip/hip_runtime.h>
#include <hip/hip_bf16.h>

#define N_NODES 131072
#define N_EDGES 524288
#define DHID    128
#define DIN     256

typedef __attribute__((ext_vector_type(8))) short short8;
typedef __attribute__((ext_vector_type(4))) float floatx4;

__device__ inline short bf16_rne(float f) {
    union { float f; unsigned u; } v; v.f = f;
    unsigned r = v.u + 0x7FFF + ((v.u >> 16) & 1);
    return (short)(r >> 16);
}
__device__ inline float bf16_to_f(short s) {
    union { unsigned u; float f; } v; v.u = ((unsigned)(unsigned short)s) << 16;
    return v.f;
}

// ---------------- CSR build ----------------

__global__ __launch_bounds__(256) void count_edges(const int* __restrict__ dst,
                                                   int* __restrict__ counts) {
    int e = blockIdx.x * 256 + threadIdx.x;
    atomicAdd(&counts[dst[e]], 1);
}

__global__ __launch_bounds__(256) void scan1(const int* __restrict__ counts,
                                             int* __restrict__ offsets,
                                             int* __restrict__ bsums) {
    __shared__ int s[256];
    int i = blockIdx.x * 256 + threadIdx.x;
    int v = counts[i];
    s[threadIdx.x] = v;
    __syncthreads();
    for (int d = 1; d < 256; d <<= 1) {
        int t = (threadIdx.x >= d) ? s[threadIdx.x - d] : 0;
        __syncthreads();
        s[threadIdx.x] += t;
        __syncthreads();
    }
    offsets[i] = s[threadIdx.x] - v;
    if (threadIdx.x == 255) bsums[blockIdx.x] = s[255];
}

__global__ __launch_bounds__(512) void scan2(int* __restrict__ bsums) {
    __shared__ int s[512];
    int v = bsums[threadIdx.x];
    s[threadIdx.x] = v;
    __syncthreads();
    for (int d = 1; d < 512; d <<= 1) {
        int t = (threadIdx.x >= d) ? s[threadIdx.x - d] : 0;
        __syncthreads();
        s[threadIdx.x] += t;
        __syncthreads();
    }
    bsums[threadIdx.x] = s[threadIdx.x] - v;
}

__global__ __launch_bounds__(256) void scan3(const int* __restrict__ counts,
                                             int* __restrict__ offsets,
                                             int* __restrict__ cursor,
                                             float* __restrict__ dinv,
                                             const int* __restrict__ bsums) {
    int i = blockIdx.x * 256 + threadIdx.x;
    int off = offsets[i] + bsums[blockIdx.x];
    offsets[i] = off;
    cursor[i]  = off;
    dinv[i] = rsqrtf((float)(counts[i] + 1));
}

// packed CSR entry: {src, bits(dinv[src])} — removes the dependent per-edge
// dinv gather from the conv inner loop (2x amortized: both conv layers read it)
__global__ __launch_bounds__(256) void fill_csr(const int* __restrict__ src,
                                                const int* __restrict__ dst,
                                                int* __restrict__ cursor,
                                                const float* __restrict__ dinv,
                                                int2* __restrict__ csr) {
    int e = blockIdx.x * 256 + threadIdx.x;
    int d = dst[e];
    int s = src[e];
    int p = atomicAdd(&cursor[d], 1);
    csr[p] = make_int2(s, __float_as_int(dinv[s]));
}

// ---------------- fp32 -> bf16 conversions (once per call) ----------------

__global__ __launch_bounds__(256) void convert_weights(const float* __restrict__ Wn,
                                                       const float* __restrict__ W1,
                                                       const float* __restrict__ W2,
                                                       short* __restrict__ Wnb,
                                                       short* __restrict__ W1b,
                                                       short* __restrict__ W2b) {
    int i = blockIdx.x * 256 + threadIdx.x;          // 65536 total
    if (i < 32768)      Wnb[i] = bf16_rne(Wn[i]);
    else if (i < 49152) W1b[i - 32768] = bf16_rne(W1[i - 32768]);
    else                W2b[i - 49152] = bf16_rne(W2[i - 49152]);
}

__global__ __launch_bounds__(256) void convert_emb(const float* __restrict__ in,
                                                   short* __restrict__ outb) {
    size_t i = (size_t)(blockIdx.x * 256 + threadIdx.x) * 8;   // 32000*256 = 8192000
    float4 v0 = *(const float4*)&in[i];
    float4 v1 = *(const float4*)&in[i + 4];
    short8 o;
    o[0] = bf16_rne(v0.x); o[1] = bf16_rne(v0.y);
    o[2] = bf16_rne(v0.z); o[3] = bf16_rne(v0.w);
    o[4] = bf16_rne(v1.x); o[5] = bf16_rne(v1.y);
    o[6] = bf16_rne(v1.z); o[7] = bf16_rne(v1.w);
    *(short8*)&outb[i] = o;
}

// ---------------- embed GEMM: out[i][:] = embb[tok[i]] @ Wn^T + bn ----------------
// Zero-LDS, zero-barrier. 4 waves/block, 32 nodes/wave, K=256, all-bf16 loads.
// B-row remap (row = col*8+ft): lane's 8 outputs across ft are CONSECUTIVE
// features -> one short8 (16B) store per row; wave stores full 256B rows.

__global__ __launch_bounds__(256) void gemm_embed(const short* __restrict__ Ab,
                                                  const int* __restrict__ tok,
                                                  const short* __restrict__ Wb,
                                                  const float* __restrict__ bias,
                                                  short* __restrict__ out) {
    const int t = threadIdx.x;
    const int wid  = t >> 6;
    const int lane = t & 63;
    const int col  = lane & 15;
    const int quad = lane >> 4;
    const int base = blockIdx.x * 128 + wid * 32;

    const size_t row0 = (size_t)tok[base + col];
    const size_t row1 = (size_t)tok[base + 16 + col];

    floatx4 acc[2][8] = {};

#pragma unroll
    for (int kc = 0; kc < DIN / 32; ++kc) {
        const int ko = kc * 32 + quad * 8;
        short8 a0 = *(const short8*)&Ab[row0 * DIN + ko];
        short8 a1 = *(const short8*)&Ab[row1 * DIN + ko];
#pragma unroll
        for (int ft = 0; ft < 8; ++ft) {
            short8 b = *(const short8*)&Wb[(size_t)(col * 8 + ft) * DIN + ko];
            acc[0][ft] = __builtin_amdgcn_mfma_f32_16x16x32_bf16(a0, b, acc[0][ft], 0, 0, 0);
            acc[1][ft] = __builtin_amdgcn_mfma_f32_16x16x32_bf16(a1, b, acc[1][ft], 0, 0, 0);
        }
    }

    const float4 bv0 = *(const float4*)&bias[col * 8];
    const float4 bv1 = *(const float4*)&bias[col * 8 + 4];
    const float bb[8] = {bv0.x, bv0.y, bv0.z, bv0.w, bv1.x, bv1.y, bv1.z, bv1.w};

#pragma unroll
    for (int mt = 0; mt < 2; ++mt) {
#pragma unroll
        for (int r = 0; r < 4; ++r) {
            const int row = base + mt * 16 + quad * 4 + r;
            short8 o;
#pragma unroll
            for (int ft = 0; ft < 8; ++ft)
                o[ft] = bf16_rne(acc[mt][ft][r] + bb[ft]);
            *(short8*)&out[(size_t)row * DHID + col * 8] = o;
        }
    }
}

// ---------------- fused GCN conv ----------------
// One wave = 16 nodes. Lane (col=lane&15, quad=lane>>4) aggregates node base+col
// in fp32 regs = the MFMA A-fragment layout. Edge loop unrolled x2 with 2-entry
// software prefetch: 8 row-gathers in flight/wave (was 4 -> MLP-bound at 2.1TB/s).
// di factored out of the loop (packed norm = dinv[src] only).

template <bool RELU, bool OUT_BF16>
__global__ __launch_bounds__(256) void fused_conv(const short* __restrict__ x,
                                                  const int2* __restrict__ csr,
                                                  const int* __restrict__ offsets,
                                                  const int* __restrict__ counts,
                                                  const float* __restrict__ dinv,
                                                  const short* __restrict__ Wb,
                                                  const float* __restrict__ bias,
                                                  void* __restrict__ outp) {
    const int t = threadIdx.x;
    const int wid  = t >> 6;
    const int lane = t & 63;
    const int col  = lane & 15;
    const int quad = lane >> 4;
    const int base = (blockIdx.x * 4 + wid) * 16;
    const int node = base + col;

    const float di = dinv[node];
    const int beg = offsets[node];
    const int cnt = counts[node];

    // self-loop init: af = di * x_self   (total = di*(di*x_self + sum dinv_s*x_s))
    float af[4][8];
    {
        const size_t xrow = (size_t)node * DHID + quad * 8;
#pragma unroll
        for (int c = 0; c < 4; ++c) {
            short8 v = *(const short8*)&x[xrow + c * 32];
#pragma unroll
            for (int j = 0; j < 8; ++j) af[c][j] = di * bf16_to_f(v[j]);
        }
    }

    // edge loop: pairs, software-pipelined packed-entry prefetch
    int2 c0 = make_int2(0, 0), c1 = make_int2(0, 0);
    if (cnt > 0) c0 = csr[beg];
    if (cnt > 1) c1 = csr[beg + 1];
    int e = 0;
    for (; e + 2 <= cnt; e += 2) {
        const int   s0 = c0.x, s1 = c1.x;
        const float w0 = __int_as_float(c0.y);
        const float w1 = __int_as_float(c1.y);
        if (e + 2 < cnt) c0 = csr[beg + e + 2];
        if (e + 3 < cnt) c1 = csr[beg + e + 3];
        const size_t r0 = (size_t)s0 * DHID + quad * 8;
        const size_t r1 = (size_t)s1 * DHID + quad * 8;
        short8 u0 = *(const short8*)&x[r0];
        short8 u1 = *(const short8*)&x[r0 + 32];
        short8 u2 = *(const short8*)&x[r0 + 64];
        short8 u3 = *(const short8*)&x[r0 + 96];
        short8 v0 = *(const short8*)&x[r1];
        short8 v1 = *(const short8*)&x[r1 + 32];
        short8 v2 = *(const short8*)&x[r1 + 64];
        short8 v3 = *(const short8*)&x[r1 + 96];
#pragma unroll
        for (int j = 0; j < 8; ++j) {
            af[0][j] = fmaf(w0, bf16_to_f(u0[j]), af[0][j]);
            af[1][j] = fmaf(w0, bf16_to_f(u1[j]), af[1][j]);
            af[2][j] = fmaf(w0, bf16_to_f(u2[j]), af[2][j]);
            af[3][j] = fmaf(w0, bf16_to_f(u3[j]), af[3][j]);
        }
#pragma unroll
        for (int j = 0; j < 8; ++j) {
            af[0][j] = fmaf(w1, bf16_to_f(v0[j]), af[0][j]);
            af[1][j] = fmaf(w1, bf16_to_f(v1[j]), af[1][j]);
            af[2][j] = fmaf(w1, bf16_to_f(v2[j]), af[2][j]);
            af[3][j] = fmaf(w1, bf16_to_f(v3[j]), af[3][j]);
        }
    }
    if (e < cnt) {   // odd tail: pending entry is in c0
        const float w0 = __int_as_float(c0.y);
        const size_t r0 = (size_t)c0.x * DHID + quad * 8;
        short8 u0 = *(const short8*)&x[r0];
        short8 u1 = *(const short8*)&x[r0 + 32];
        short8 u2 = *(const short8*)&x[r0 + 64];
        short8 u3 = *(const short8*)&x[r0 + 96];
#pragma unroll
        for (int j = 0; j < 8; ++j) {
            af[0][j] = fmaf(w0, bf16_to_f(u0[j]), af[0][j]);
            af[1][j] = fmaf(w0, bf16_to_f(u1[j]), af[1][j]);
            af[2][j] = fmaf(w0, bf16_to_f(u2[j]), af[2][j]);
            af[3][j] = fmaf(w0, bf16_to_f(u3[j]), af[3][j]);
        }
    }

    // fold the outer di and round aggregated A-fragments to bf16
    short8 a[4];
#pragma unroll
    for (int c = 0; c < 4; ++c)
#pragma unroll
        for (int j = 0; j < 8; ++j) a[c][j] = bf16_rne(di * af[c][j]);

    // MFMA with weights (L1-hot). B-row remap: row = col*8+ft so lane's outputs
    // across ft are consecutive features.
    floatx4 acc[8] = {};
#pragma unroll
    for (int c = 0; c < 4; ++c) {
        const int ko = c * 32 + quad * 8;
#pragma unroll
        for (int ft = 0; ft < 8; ++ft) {
            short8 b = *(const short8*)&Wb[(size_t)(col * 8 + ft) * DHID + ko];
            acc[ft] = __builtin_amdgcn_mfma_f32_16x16x32_bf16(a[c], b, acc[ft], 0, 0, 0);
        }
    }

    // epilogue: lane (col,quad) holds D rows quad*4+r, features col*8..col*8+7
    // -> contiguous 16B (bf16) / 32B (fp32) store per row, full 256B wave rows.
    const float4 bv0 = *(const float4*)&bias[col * 8];
    const float4 bv1 = *(const float4*)&bias[col * 8 + 4];
    const float bb[8] = {bv0.x, bv0.y, bv0.z, bv0.w, bv1.x, bv1.y, bv1.z, bv1.w};
    short* outb = (short*)outp;
    float* outf = (float*)outp;
#pragma unroll
    for (int r = 0; r < 4; ++r) {
        const size_t row = (size_t)(base + quad * 4 + r) * DHID + col * 8;
        if (OUT_BF16) {
            short8 o;
#pragma unroll
            for (int ft = 0; ft < 8; ++ft) {
                float v = acc[ft][r] + bb[ft];
                if (RELU) v = fmaxf(v, 0.f);
                o[ft] = bf16_rne(v);
            }
            *(short8*)&outb[row] = o;
        } else {
            float4 o0, o1;
            o0.x = acc[0][r] + bb[0]; o0.y = acc[1][r] + bb[1];
            o0.z = acc[2][r] + bb[2]; o0.w = acc[3][r] + bb[3];
            o1.x = acc[4][r] + bb[4]; o1.y = acc[5][r] + bb[5];
            o1.z = acc[6][r] + bb[6]; o1.w = acc[7][r] + bb[7];
            if (RELU) {
                o0.x = fmaxf(o0.x, 0.f); o0.y = fmaxf(o0.y, 0.f);
                o0.z = fmaxf(o0.z, 0.f); o0.w = fmaxf(o0.w, 0.f);
                o1.x = fmaxf(o1.x, 0.f); o1.y = fmaxf(o1.y, 0.f);
                o1.z = fmaxf(o1.z, 0.f); o1.w = fmaxf(o1.w, 0.f);
            }
            *(float4*)&outf[row] = o0;
            *(float4*)&outf[row + 4] = o1;
        }
    }
}

// ---------------- metadata outputs ----------------

__global__ __launch_bounds__(256) void meta_kernel(const int* __restrict__ tok,
                                                   float* __restrict__ out) {
    int i = blockIdx.x * 256 + threadIdx.x;
    const size_t L0 = (size_t)N_NODES * DHID;
    out[L0 + i]               = (float)tok[i];
    out[L0 + N_NODES + i]     = 1.0f;
    out[L0 + 2 * N_NODES + i] = (float)(i & 2047);
}

// ---------------- launch ----------------

extern "C" void kernel_launch(void* const* d_in, const int* in_sizes, int n_in,
                              void* d_out, int out_size, void* d_ws, size_t ws_size,
                              hipStream_t stream) {
    const int*   tok  = (const int*)d_in[0];
    const int*   esrc = (const int*)d_in[1];
    const int*   edst = esrc + N_EDGES;
    const float* emb  = (const float*)d_in[2];
    const float* Wn   = (const float*)d_in[3];
    const float* bn   = (const float*)d_in[4];
    const float* W1   = (const float*)d_in[5];
    const float* b1   = (const float*)d_in[6];
    const float* W2   = (const float*)d_in[7];
    const float* b2   = (const float*)d_in[8];
    float* out = (float*)d_out;

    char* ws = (char*)d_ws;
    int*   counts  = (int*)(ws);                              // 512 KB @0
    int*   offsets = (int*)(ws + (1u << 19));                 // 512 KB
    int*   cursor  = (int*)(ws + (2u << 19));                 // 512 KB
    float* dinv    = (float*)(ws + (3u << 19));               // 512 KB
    int*   bsums   = (int*)(ws + (4u << 19));                 // 2 KB
    int2*  csr     = (int2*)(ws + 3 * (1u << 20));            // 4 MB @3MB (packed {src,norm})
    short* Wnb     = (short*)(ws + 7 * (1u << 20));           // 64 KB @7MB
    short* W1b     = (short*)(ws + 7 * (1u << 20) + (1u << 16)); // 32 KB
    short* W2b     = (short*)(ws + 7 * (1u << 20) + 96 * 1024);  // 32 KB
    short* embb    = (short*)(ws + 7 * (1u << 20) + (1u << 18)); // 16.4 MB @7.25MB (ends ~23.6MB)
    short* x2b     = (short*)(ws + 24 * (1u << 20));          // 33.5 MB @24MB (ends ~58MB)
    short* xb      = (short*)d_out;                           // 33.5 MB scratch in d_out

    hipMemsetAsync(counts, 0, N_NODES * sizeof(int), stream);
    count_edges<<<N_EDGES / 256, 256, 0, stream>>>(edst, counts);
    scan1<<<N_NODES / 256, 256, 0, stream>>>(counts, offsets, bsums);
    scan2<<<1, 512, 0, stream>>>(bsums);
    scan3<<<N_NODES / 256, 256, 0, stream>>>(counts, offsets, cursor, dinv, bsums);
    fill_csr<<<N_EDGES / 256, 256, 0, stream>>>(esrc, edst, cursor, dinv, csr);
    convert_weights<<<65536 / 256, 256, 0, stream>>>(Wn, W1, W2, Wnb, W1b, W2b);
    convert_emb<<<(32000 * 256 / 8) / 256, 256, 0, stream>>>(emb, embb);

    // x = bf16(embb[tok] @ Wn^T + bn) -> xb (d_out scratch)
    gemm_embed<<<N_NODES / 128, 256, 0, stream>>>(embb, tok, Wnb, bn, xb);
    // conv1: fused aggregate+GEMM, relu, bf16 out -> x2b
    fused_conv<true, true><<<N_NODES / 64, 256, 0, stream>>>(
        xb, csr, offsets, counts, dinv, W1b, b1, x2b);
    // conv2: fused, fp32 out straight to d_out (overwrites xb scratch; reads only x2b)
    fused_conv<false, false><<<N_NODES / 64, 256, 0, stream>>>(
        x2b, csr, offsets, counts, dinv, W2b, b2, out);

    meta_kernel<<<N_NODES / 256, 256, 0, stream>>>(tok, out);
}